// Round 14
// baseline (544.538 us; speedup 1.0000x reference)
//
#include <hip/hip_runtime.h>

typedef unsigned short u16;
typedef unsigned int u32;

#define NN 8192
#define CAP 128

typedef __attribute__((ext_vector_type(8))) short short8;
typedef __attribute__((ext_vector_type(4))) float floatx4;

__device__ __forceinline__ u16 f2bf(float f) {
    union { float f; u32 i; } w;
    w.f = f;
    u32 i = w.i;
    u32 r = (i + 0x7FFFu + ((i >> 16) & 1u)) >> 16;
    return (u16)r;
}
__device__ __forceinline__ float lo_bf(u32 v) {
    union { u32 i; float f; } w;
    w.i = v << 16;
    return w.f;
}
__device__ __forceinline__ float hi_bf(u32 v) {
    union { u32 i; float f; } w;
    w.i = v & 0xFFFF0000u;
    return w.f;
}
__device__ __forceinline__ float softplusf(float x) {
    return fmaxf(x, 0.0f) + log1pf(expf(-fabsf(x)));
}

// ---------------- PROLOGUE MEGA-KERNEL ----------------
// Blocks 0..2047:   build_graph (wave-per-row edge list + degree + rsqrt norm)
//                   then concat+scale the same 4 rows' features.
// Blocks 2048..3071: 32x32 weight transposes f32->bf16 (ride along ~free
//                   under the HBM-bound adjacency stream).
__global__ __launch_bounds__(256) void prologue(
    const float* __restrict__ adj,
    const float* __restrict__ emb, const float* __restrict__ pos,
    const float* __restrict__ W0, const float* __restrict__ W1,
    const float* __restrict__ W2, const float* __restrict__ W3,
    u16* __restrict__ T0, u16* __restrict__ T1,
    u16* __restrict__ T2, u16* __restrict__ T3,
    int* __restrict__ deg, float* __restrict__ snorm,
    u32* __restrict__ edges, u16* __restrict__ feat0)
{
    __shared__ char shraw[32 * 33 * 4];   // union: cnt[4] (build) | tile[32][33] (transpose)
    const int b = blockIdx.x;

    if (b < 2048) {
        int* cnt = (int*)shraw;
        const int wave = threadIdx.x >> 6, lane = threadIdx.x & 63;
        const int i = b * 4 + wave;
        if (threadIdx.x < 4) cnt[threadIdx.x] = 0;
        __syncthreads();
        const uint4* rowp = (const uint4*)(adj + (size_t)i * NN);
        u32* erow = edges + (size_t)i * CAP;
#pragma unroll 4
        for (int it = 0; it < 32; ++it) {            // 32 * 64 lanes * 4 f32 = 8192
            uint4 v = rowp[it * 64 + lane];
            int jb = (it * 64 + lane) * 4;
            u32 w[4] = { v.x, v.y, v.z, v.w };
#pragma unroll
            for (int e = 0; e < 4; ++e) {
                int j = jb + e;
                if ((i != j) && ((w[e] & 0x7FFFFFFFu) != 0)) {
                    int slot = atomicAdd(&cnt[wave], 1);   // LDS atomic, wave-local
                    if (slot < CAP) erow[slot] = (u32)j;
                }
            }
        }
        __syncthreads();
        int c = cnt[wave];
        float s = rsqrtf((float)max(c, 1));
        if (lane == 0) { deg[i] = c; snorm[i] = s; }
#pragma unroll
        for (int h = 0; h < 2; ++h) {
            int f = lane + h * 64;
            float v = (f < 125) ? emb[(size_t)i * 125 + f] : pos[(size_t)i * 3 + (f - 125)];
            feat0[(size_t)i * 128 + f] = f2bf(v * s);
        }
    } else {
        float (*tile)[33] = (float(*)[33])shraw;
        int b2 = b - 2048;
        int z = b2 >> 8, rem = b2 & 255;
        const float* W = (z == 0) ? W0 : (z == 1) ? W1 : (z == 2) ? W2 : W3;
        u16* WT       = (z == 0) ? T0 : (z == 1) ? T1 : (z == 2) ? T2 : T3;
        const int K = (z == 0) ? 128 : 512;
        const int N = 512;
        int bx = (rem & 15) * 32;   // n
        int by = (rem >> 4) * 32;   // k
        if (by >= K) return;        // block-uniform
        int tx = threadIdx.x & 31, ty = threadIdx.x >> 5;
#pragma unroll
        for (int yy = ty; yy < 32; yy += 8)
            tile[yy][tx] = W[(size_t)(by + yy) * N + bx + tx];
        __syncthreads();
#pragma unroll
        for (int yy = ty; yy < 32; yy += 8)
            WT[(size_t)(bx + yy) * K + by + tx] = f2bf(tile[tx][yy]);
    }
}

// ---------------- SpMM F=512 ----------------
__global__ __launch_bounds__(256) void spmm512(
    const u32* __restrict__ edges, const int* __restrict__ deg,
    const float* __restrict__ snorm,
    const uint4* __restrict__ feat4, uint4* __restrict__ out4)
{
    __shared__ int sh_i[4][CAP];
    const int wave = threadIdx.x >> 6, lane = threadIdx.x & 63;
    const int j = blockIdx.x * 4 + wave;
    const int cnt = min(deg[j], CAP);
    for (int c = lane; c < cnt; c += 64)
        sh_i[wave][c] = (int)edges[(size_t)j * CAP + c];
    __syncthreads();
    float a[8] = {};
#pragma unroll 4
    for (int c = 0; c < cnt; ++c) {
        uint4 v = feat4[(size_t)sh_i[wave][c] * 64 + lane];   // 512 cols = 64 uint4
        a[0] += lo_bf(v.x); a[1] += hi_bf(v.x);
        a[2] += lo_bf(v.y); a[3] += hi_bf(v.y);
        a[4] += lo_bf(v.z); a[5] += hi_bf(v.z);
        a[6] += lo_bf(v.w); a[7] += hi_bf(v.w);
    }
    float sj = snorm[j];
    uint4 o;
    o.x = (u32)f2bf(a[0] * sj) | ((u32)f2bf(a[1] * sj) << 16);
    o.y = (u32)f2bf(a[2] * sj) | ((u32)f2bf(a[3] * sj) << 16);
    o.z = (u32)f2bf(a[4] * sj) | ((u32)f2bf(a[5] * sj) << 16);
    o.w = (u32)f2bf(a[6] * sj) | ((u32)f2bf(a[7] * sj) << 16);
    out4[(size_t)j * 64 + lane] = o;
}

// ---------------- SpMM F=128 (layer 0) ----------------
__global__ __launch_bounds__(256) void spmm128(
    const u32* __restrict__ edges, const int* __restrict__ deg,
    const float* __restrict__ snorm,
    const u32* __restrict__ feat1, u32* __restrict__ out1)
{
    __shared__ int sh_i[4][CAP];
    const int wave = threadIdx.x >> 6, lane = threadIdx.x & 63;
    const int j = blockIdx.x * 4 + wave;
    const int cnt = min(deg[j], CAP);
    for (int c = lane; c < cnt; c += 64)
        sh_i[wave][c] = (int)edges[(size_t)j * CAP + c];
    __syncthreads();
    float a0 = 0.f, a1 = 0.f;
#pragma unroll 4
    for (int c = 0; c < cnt; ++c) {
        u32 v = feat1[(size_t)sh_i[wave][c] * 64 + lane];   // 128 cols = 64 u32
        a0 += lo_bf(v); a1 += hi_bf(v);
    }
    float sj = snorm[j];
    out1[(size_t)j * 64 + lane] = (u32)f2bf(a0 * sj) | ((u32)f2bf(a1 * sj) << 16);
}

// ---------------- GEMM: out = softplus(A[M,K] @ W + b) [* snorm[row] inner layers] ----------------
// BM=64, BN=64, BK=128 -> 4 K-iters (was 8): half the vmcnt(0)+barrier drains.
// 1024 blocks = 4/CU (32KB LDS, cap 5). 16-slot XOR swizzle: LDS slot s of row
// r holds global k-block s ^ (r&15) -> conflict-free ds_read_b128 (8-lane
// phases hit 8 distinct bank-groups; 2-way alias is free per m136).
__global__ __launch_bounds__(256, 4) void gemm_bias_softplus(
    const u16* __restrict__ A, const u16* __restrict__ BT,
    const float* __restrict__ bias, const float* __restrict__ snorm,
    float* __restrict__ outf, u16* __restrict__ outb,
    int M, int N, int K)
{
    __shared__ u16 lA[64 * 128];   // [row][k] 16KB, swizzled 16-slot rows
    __shared__ u16 lB[64 * 128];   // [col][k] 16KB
    const int tid = threadIdx.x;
    const int wave = tid >> 6;
    const int lane = tid & 63;
    const int q = lane >> 4;
    const int m16 = lane & 15;
    const int wm = (wave >> 1) * 32;
    const int wn = (wave & 1) * 32;
    const int bm = blockIdx.x, bn = blockIdx.y;

    // staging: pass p covers rows p*16 + (tid>>4), slot = tid&15
    const int srow = tid >> 4;            // 0..15 row within pass
    const int g    = (tid & 15) ^ srow;   // swizzled global k-block (row&15 == srow)
    const u16* gA = A  + (size_t)(bm * 64 + srow) * K + g * 8;
    const u16* gB = BT + (size_t)(bn * 64 + srow) * K + g * 8;
    const size_t rowstep = (size_t)16 * K;          // +16 rows per pass
    u16* lAp = lA + tid * 8;                        // +2048 u16 per pass
    u16* lBp = lB + tid * 8;

    floatx4 acc[2][2] = {};

    for (int k0 = 0; k0 < K; k0 += 128) {
#pragma unroll
        for (int ps = 0; ps < 4; ++ps) {
            __builtin_amdgcn_global_load_lds(
                (const __attribute__((address_space(1))) u32*)(const void*)(gA + ps * rowstep + k0),
                (__attribute__((address_space(3))) u32*)(void*)(lAp + ps * 2048), 16, 0, 0);
            __builtin_amdgcn_global_load_lds(
                (const __attribute__((address_space(1))) u32*)(const void*)(gB + ps * rowstep + k0),
                (__attribute__((address_space(3))) u32*)(void*)(lBp + ps * 2048), 16, 0, 0);
        }
        __syncthreads();   // barrier semantics drain vmcnt first

#pragma unroll
        for (int kk = 0; kk < 4; ++kk) {
            short8 af[2], bfr[2];
#pragma unroll
            for (int im = 0; im < 2; ++im) {
                int row = wm + im * 16 + m16;
                int slot = (kk * 4 + q) ^ m16;      // row&15 == m16
                af[im] = *(const short8*)&lA[row * 128 + slot * 8];
            }
#pragma unroll
            for (int in = 0; in < 2; ++in) {
                int row = wn + in * 16 + m16;
                int slot = (kk * 4 + q) ^ m16;
                bfr[in] = *(const short8*)&lB[row * 128 + slot * 8];
            }
#pragma unroll
            for (int im = 0; im < 2; ++im)
#pragma unroll
                for (int in = 0; in < 2; ++in)
                    acc[im][in] = __builtin_amdgcn_mfma_f32_16x16x32_bf16(
                        af[im], bfr[in], acc[im][in], 0, 0, 0);
        }
        __syncthreads();
    }

    // epilogue: C/D layout col = lane&15, row = q*4 + reg  [measured m89/m91]
#pragma unroll
    for (int im = 0; im < 2; ++im) {
#pragma unroll
        for (int in = 0; in < 2; ++in) {
            int col = bn * 64 + wn + in * 16 + m16;
            float bvf = bias[col];
#pragma unroll
            for (int r = 0; r < 4; ++r) {
                int row = bm * 64 + wm + im * 16 + q * 4 + r;
                float v = softplusf(acc[im][in][r] + bvf);
                if (outf) outf[(size_t)row * N + col] = v;
                else      outb[(size_t)row * N + col] = f2bf(v * snorm[row]);
            }
        }
    }
}

extern "C" void kernel_launch(void* const* d_in, const int* in_sizes, int n_in,
                              void* d_out, int out_size, void* d_ws, size_t ws_size,
                              hipStream_t stream)
{
    const float* atom_pos = (const float*)d_in[0];
    const float* dist_adj = (const float*)d_in[1];
    const float* atom_emb = (const float*)d_in[2];
    const float* Wm[4] = { (const float*)d_in[3], (const float*)d_in[5],
                           (const float*)d_in[7], (const float*)d_in[9] };
    const float* bv[4] = { (const float*)d_in[4], (const float*)d_in[6],
                           (const float*)d_in[8], (const float*)d_in[10] };

    char* p = (char*)d_ws;
    auto alloc = [&](size_t n) { char* r = p; p += (n + 255) & ~(size_t)255; return r; };
    int*   deg   = (int*)alloc(NN * 4);
    float* snorm = (float*)alloc(NN * 4);
    u32*   edges = (u32*)alloc((size_t)NN * CAP * 4);
    u16*   wt[4];
    wt[0] = (u16*)alloc(512 * 128 * 2);
    wt[1] = (u16*)alloc(512 * 512 * 2);
    wt[2] = (u16*)alloc(512 * 512 * 2);
    wt[3] = (u16*)alloc(512 * 512 * 2);
    u16* buf0 = (u16*)alloc((size_t)NN * 512 * 2);
    u16* buf1 = (u16*)alloc((size_t)NN * 512 * 2);

    prologue<<<2048 + 1024, 256, 0, stream>>>(
        dist_adj, atom_emb, atom_pos,
        Wm[0], Wm[1], Wm[2], Wm[3], wt[0], wt[1], wt[2], wt[3],
        deg, snorm, edges, buf0);

    const u16* feat = buf0;
    int F = 128;
    for (int l = 0; l < 4; ++l) {
        if (F == 128)
            spmm128<<<NN / 4, 256, 0, stream>>>(edges, deg, snorm,
                                                (const u32*)feat, (u32*)buf1);
        else
            spmm512<<<NN / 4, 256, 0, stream>>>(edges, deg, snorm,
                                                (const uint4*)feat, (uint4*)buf1);
        float* outf = (l == 3) ? (float*)d_out : nullptr;
        u16*   outb = (l == 3) ? nullptr : buf0;
        gemm_bias_softplus<<<dim3(NN / 64, 512 / 64), 256, 0, stream>>>(
            buf1, wt[l], bv[l], snorm, outf, outb, NN, 512, F);
        feat = buf0;
        F = 512;
    }
}